// Round 1
// baseline (4514.198 us; speedup 1.0000x reference)
//
#include <hip/hip_runtime.h>

#define CH     16
#define HID    128
#define HWDIM  128
#define NB     32
#define NSTEPS 32

// ---------------------------------------------------------------------------
// One NCA step: perception (identity + sobel dx/dy) -> fc0+relu -> fc1 -> masked
// residual update.  One thread per pixel, 16x16 pixel tile per 256-thread block,
// halo tile staged in LDS channel-major to keep stencil reads conflict-free.
// ---------------------------------------------------------------------------
__global__ __launch_bounds__(256) void nca_step(
    const float* __restrict__ xin, float* __restrict__ xout,
    const float* __restrict__ mask,
    const float* __restrict__ fc0_w, const float* __restrict__ fc0_b,
    const float* __restrict__ fc1_w)
{
    __shared__ float tile[CH][18][18];   // 20736 B, channel-major: stencil reads ~conflict-free
    const int b  = blockIdx.z;
    const int y0 = blockIdx.y * 16, x0 = blockIdx.x * 16;
    const int tid = threadIdx.x;

    // ---- stage 18x18 halo tile (zero 'SAME' padding at image edges) ----
    for (int q = tid; q < 18 * 18 * 4; q += 256) {
        const int c4 = q & 3;          // which float4 channel group
        const int p  = q >> 2;         // pixel 0..323
        const int i  = p / 18, j = p - i * 18;
        const int gy = y0 - 1 + i, gx = x0 - 1 + j;
        float4 v = make_float4(0.f, 0.f, 0.f, 0.f);
        if ((unsigned)gy < HWDIM && (unsigned)gx < HWDIM) {
            v = *reinterpret_cast<const float4*>(
                &xin[(((size_t)b * HWDIM + gy) * HWDIM + gx) * CH + c4 * 4]);
        }
        tile[c4 * 4 + 0][i][j] = v.x;
        tile[c4 * 4 + 1][i][j] = v.y;
        tile[c4 * 4 + 2][i][j] = v.z;
        tile[c4 * 4 + 3][i][j] = v.w;
    }
    __syncthreads();

    const int j  = tid & 15, i = tid >> 4;
    const int li = i + 1,  lj = j + 1;

    // ---- perception vector y[48] = [x, sobel_dx(x), sobel_dy(x)] ----
    float y[48];
    #pragma unroll
    for (int c = 0; c < CH; ++c) {
        const float n00 = tile[c][li-1][lj-1], n01 = tile[c][li-1][lj], n02 = tile[c][li-1][lj+1];
        const float n10 = tile[c][li  ][lj-1], n11 = tile[c][li  ][lj], n12 = tile[c][li  ][lj+1];
        const float n20 = tile[c][li+1][lj-1], n21 = tile[c][li+1][lj], n22 = tile[c][li+1][lj+1];
        y[c]        = n11;
        y[16 + c]   = ((n02 - n00) + 2.f * (n12 - n10) + (n22 - n20)) * 0.125f;
        y[32 + c]   = ((n20 - n00) + 2.f * (n21 - n01) + (n22 - n02)) * 0.125f;
    }

    // ---- fc0 (48->128) + relu, fused fc1 (128->16) accumulate ----
    float d[CH];
    #pragma unroll
    for (int c = 0; c < CH; ++c) d[c] = 0.f;

    for (int o = 0; o < HID; ++o) {       // wave-uniform index -> scalar loads
        float h = fc0_b[o];
        #pragma unroll
        for (int k = 0; k < 48; ++k) h += fc0_w[o * 48 + k] * y[k];
        h = fmaxf(h, 0.f);
        #pragma unroll
        for (int c = 0; c < CH; ++c) d[c] += fc1_w[c * HID + o] * h;
    }

    // ---- masked residual update (first 3 channels frozen) ----
    const int py = y0 + i, px = x0 + j;
    const float m = mask[((size_t)b * HWDIM + py) * HWDIM + px];
    float* op = &xout[(((size_t)b * HWDIM + py) * HWDIM + px) * CH];

    float4 r0;
    r0.x = y[0];                 // frozen
    r0.y = y[1];                 // frozen
    r0.z = y[2];                 // frozen
    r0.w = y[3] + d[3] * m;
    reinterpret_cast<float4*>(op)[0] = r0;
    #pragma unroll
    for (int q = 1; q < 4; ++q) {
        float4 t;
        t.x = y[q*4+0] + d[q*4+0] * m;
        t.y = y[q*4+1] + d[q*4+1] * m;
        t.z = y[q*4+2] + d[q*4+2] * m;
        t.w = y[q*4+3] + d[q*4+3] * m;
        reinterpret_cast<float4*>(op)[q] = t;
    }
}

// ---------------------------------------------------------------------------
// Mean-pool over H,W: one block per batch element.
// ---------------------------------------------------------------------------
__global__ __launch_bounds__(256) void nca_pool(
    const float* __restrict__ xf, float* __restrict__ pooled)
{
    __shared__ float red[256 * CH];      // 16 KiB
    const int b = blockIdx.x, tid = threadIdx.x;
    float acc[CH];
    #pragma unroll
    for (int c = 0; c < CH; ++c) acc[c] = 0.f;

    for (int p = tid; p < HWDIM * HWDIM; p += 256) {
        const float4* px = reinterpret_cast<const float4*>(
            &xf[((size_t)b * HWDIM * HWDIM + p) * CH]);
        #pragma unroll
        for (int q = 0; q < 4; ++q) {
            const float4 v = px[q];
            acc[q*4+0] += v.x; acc[q*4+1] += v.y;
            acc[q*4+2] += v.z; acc[q*4+3] += v.w;
        }
    }
    #pragma unroll
    for (int c = 0; c < CH; ++c) red[tid * CH + c] = acc[c];
    __syncthreads();
    for (int off = 128; off > 0; off >>= 1) {
        if (tid < off) {
            #pragma unroll
            for (int c = 0; c < CH; ++c)
                red[tid * CH + c] += red[(tid + off) * CH + c];
        }
        __syncthreads();
    }
    if (tid < CH)
        pooled[b * CH + tid] = red[tid] * (1.f / (HWDIM * HWDIM));
}

// ---------------------------------------------------------------------------
// Classifier head: out = relu(pooled @ fc2^T + b2) @ fc3^T + b3   (tiny)
// ---------------------------------------------------------------------------
__global__ __launch_bounds__(128) void nca_head(
    const float* __restrict__ pooled,
    const float* __restrict__ fc2_w, const float* __restrict__ fc2_b,
    const float* __restrict__ fc3_w, const float* __restrict__ fc3_b,
    float* __restrict__ out)
{
    __shared__ float h2[HID];
    __shared__ float pl[CH];
    const int tid = threadIdx.x;
    for (int b = 0; b < NB; ++b) {
        if (tid < CH) pl[tid] = pooled[b * CH + tid];
        __syncthreads();
        float h = fc2_b[tid];
        #pragma unroll
        for (int c = 0; c < CH; ++c) h += fc2_w[tid * CH + c] * pl[c];
        h2[tid] = fmaxf(h, 0.f);
        __syncthreads();
        if (tid < 13) {
            float o = fc3_b[tid];
            #pragma unroll
            for (int jj = 0; jj < HID; ++jj) o += fc3_w[tid * HID + jj] * h2[jj];
            out[b * 13 + tid] = o;
        }
        __syncthreads();
    }
}

// ---------------------------------------------------------------------------
extern "C" void kernel_launch(void* const* d_in, const int* in_sizes, int n_in,
                              void* d_out, int out_size, void* d_ws, size_t ws_size,
                              hipStream_t stream)
{
    const float* x     = (const float*)d_in[0];
    const float* masks = (const float*)d_in[1];
    const float* fc0_w = (const float*)d_in[2];
    const float* fc0_b = (const float*)d_in[3];
    const float* fc1_w = (const float*)d_in[4];
    const float* fc2_w = (const float*)d_in[5];
    const float* fc2_b = (const float*)d_in[6];
    const float* fc3_w = (const float*)d_in[7];
    const float* fc3_b = (const float*)d_in[8];

    float* out    = (float*)d_out;
    float* xf     = out + NB * 13;                                  // output 1 region
    float* buf0   = (float*)d_ws;                                   // ping-pong buffer
    float* pooled = buf0 + (size_t)NB * HWDIM * HWDIM * CH;         // 512 floats

    dim3 grid(HWDIM / 16, HWDIM / 16, NB), block(256);
    for (int s = 0; s < NSTEPS; ++s) {
        // ping-pong: even steps write ws, odd steps write d_out's xf region;
        // step 31 (odd) lands the final state in d_out.
        const float* in = (s == 0) ? x : ((s & 1) ? buf0 : xf);
        float* outp     = (s & 1) ? xf : buf0;
        const float* mk = masks + (size_t)s * NB * HWDIM * HWDIM;
        nca_step<<<grid, block, 0, stream>>>(in, outp, mk, fc0_w, fc0_b, fc1_w);
    }
    nca_pool<<<NB, 256, 0, stream>>>(xf, pooled);
    nca_head<<<1, 128, 0, stream>>>(pooled, fc2_w, fc2_b, fc3_w, fc3_b, out);
}

// Round 2
// 1525.424 us; speedup vs baseline: 2.9593x; 2.9593x over previous
//
#include <hip/hip_runtime.h>

#define CH     16
#define HID    128
#define HWDIM  128
#define NB     32
#define NSTEPS 32

typedef float    f32x4 __attribute__((ext_vector_type(4)));
typedef _Float16 f16x8 __attribute__((ext_vector_type(8)));

// ---------------------------------------------------------------------------
// Prepack weights into per-lane MFMA fragment order (fp16).
// A/B frag layout (16x16x32): lane l -> row/col = l&15, k = 8*(l>>4)+j, j=0..7.
// pw0: 16 frags, f = n*2+ks (n = hidden N-tile 0..7, ks = K-step 0..1, K padded 48->64)
// pw1: 4 frags,  f = ks (K-step over 128)
// pb0: bias replicated per lane: pb0[n*64+l] = fc0_b[16n + (l&15)]
// ---------------------------------------------------------------------------
__global__ __launch_bounds__(256) void nca_prepack(
    const float* __restrict__ w0, const float* __restrict__ b0,
    const float* __restrict__ w1,
    _Float16* __restrict__ pw0, _Float16* __restrict__ pw1, float* __restrict__ pb0)
{
    const int tid = threadIdx.x;
    for (int s = tid; s < 16 * 64; s += 256) {
        const int f = s >> 6, l = s & 63;
        const int n = f >> 1, ks = f & 1;
        const int o = 16 * n + (l & 15);
        f16x8 v;
        #pragma unroll
        for (int j = 0; j < 8; ++j) {
            const int k = 32 * ks + 8 * (l >> 4) + j;
            v[j] = (_Float16)(k < 48 ? w0[o * 48 + k] : 0.f);
        }
        *reinterpret_cast<f16x8*>(&pw0[s * 8]) = v;
    }
    for (int s = tid; s < 4 * 64; s += 256) {
        const int ks = s >> 6, l = s & 63;
        f16x8 v;
        #pragma unroll
        for (int j = 0; j < 8; ++j) {
            const int k = 32 * ks + 8 * (l >> 4) + j;
            v[j] = (_Float16)w1[(l & 15) * 128 + k];
        }
        *reinterpret_cast<f16x8*>(&pw1[s * 8]) = v;
    }
    for (int s = tid; s < 8 * 64; s += 256)
        pb0[s] = b0[16 * (s >> 6) + (s & 15)];
}

// ---------------------------------------------------------------------------
// One NCA step with MFMA matmuls.
// LDS phases: [halo f32 | perception] -> [ybuf f16 | MFMA chunks use hbuf
// (overlaps halo)] -> [dbuf f32 (overlaps ybuf) | epilogue].
// ---------------------------------------------------------------------------
__global__ __launch_bounds__(256, 2) void nca_step(
    const float* __restrict__ xin, float* __restrict__ xout,
    const float* __restrict__ mask,
    const _Float16* __restrict__ pw0, const float* __restrict__ pb0,
    const _Float16* __restrict__ pw1)
{
    __shared__ _Float16 ybuf[256][72];                 // 36864 B (cols 48..63 zeroed; reused as f32 dbuf[256][20])
    __shared__ __align__(16) char upool[16 * 18 * 18 * 4];  // 20736 B: halo f32, then hbuf f16
    float    (*halo)[18][18] = reinterpret_cast<float(*)[18][18]>(upool);     // [16][18][18]
    _Float16 (*hbuf)[64][40] = reinterpret_cast<_Float16(*)[64][40]>(upool);  // [4][64][40] = 20480 B

    const int bz = blockIdx.z;
    const int y0 = blockIdx.y * 16, x0 = blockIdx.x * 16;
    const int tid = threadIdx.x;

    // ---- stage 18x18 fp32 halo (zero 'SAME' padding) ----
    for (int q = tid; q < 18 * 18 * 4; q += 256) {
        const int c4 = q & 3, p = q >> 2;
        const int i = p / 18, j = p - i * 18;
        const int gy = y0 - 1 + i, gx = x0 - 1 + j;
        float4 v = make_float4(0.f, 0.f, 0.f, 0.f);
        if ((unsigned)gy < HWDIM && (unsigned)gx < HWDIM)
            v = *reinterpret_cast<const float4*>(
                &xin[(((size_t)bz * HWDIM + gy) * HWDIM + gx) * CH + c4 * 4]);
        halo[c4 * 4 + 0][i][j] = v.x;
        halo[c4 * 4 + 1][i][j] = v.y;
        halo[c4 * 4 + 2][i][j] = v.z;
        halo[c4 * 4 + 3][i][j] = v.w;
    }
    __syncthreads();

    // ---- perception in fp32, cast y -> fp16 into ybuf ----
    {
        const int j = tid & 15, i = tid >> 4;
        const int li = i + 1, lj = j + 1;
        _Float16 yv[48];
        #pragma unroll
        for (int c = 0; c < CH; ++c) {
            const float n00 = halo[c][li-1][lj-1], n01 = halo[c][li-1][lj], n02 = halo[c][li-1][lj+1];
            const float n10 = halo[c][li  ][lj-1],                          n12 = halo[c][li  ][lj+1];
            const float n20 = halo[c][li+1][lj-1], n21 = halo[c][li+1][lj], n22 = halo[c][li+1][lj+1];
            yv[c]      = (_Float16)halo[c][li][lj];
            yv[16 + c] = (_Float16)(((n02 - n00) + 2.f * (n12 - n10) + (n22 - n20)) * 0.125f);
            yv[32 + c] = (_Float16)(((n20 - n00) + 2.f * (n21 - n01) + (n22 - n02)) * 0.125f);
        }
        #pragma unroll
        for (int q = 0; q < 6; ++q) {
            f16x8 t;
            #pragma unroll
            for (int e = 0; e < 8; ++e) t[e] = yv[q * 8 + e];
            *reinterpret_cast<f16x8*>(&ybuf[tid][q * 8]) = t;
        }
        f16x8 zz;
        #pragma unroll
        for (int e = 0; e < 8; ++e) zz[e] = (_Float16)0.f;
        *reinterpret_cast<f16x8*>(&ybuf[tid][48]) = zz;   // K-pad 48..63 = 0
        *reinterpret_cast<f16x8*>(&ybuf[tid][56]) = zz;
    }
    __syncthreads();    // ybuf ready; halo dead (hbuf may now overwrite upool)

    const int w  = tid >> 6, l = tid & 63;
    const int lr = l & 15,  g = l >> 4;

    // ---- A fragments (Y), wave-private rows: afrag[t*2+ks] ----
    f16x8 afrag[8];
    #pragma unroll
    for (int t = 0; t < 4; ++t)
        #pragma unroll
        for (int ks = 0; ks < 2; ++ks)
            afrag[t * 2 + ks] = *reinterpret_cast<const f16x8*>(
                &ybuf[64 * w + 16 * t + lr][32 * ks + 8 * g]);

    // ---- fc1 B fragments + bias (L1-resident, coalesced) ----
    f16x8 b1f[4];
    #pragma unroll
    for (int ks = 0; ks < 4; ++ks)
        b1f[ks] = *reinterpret_cast<const f16x8*>(&pw1[(ks * 64 + l) * 8]);
    float bias_n[8];
    #pragma unroll
    for (int n = 0; n < 8; ++n) bias_n[n] = pb0[n * 64 + l];

    f32x4 dacc[4];
    #pragma unroll
    for (int t = 0; t < 4; ++t)
        #pragma unroll
        for (int r = 0; r < 4; ++r) dacc[t][r] = 0.f;

    // ---- 4 chunks of 32 hidden: fc0 MFMA -> relu+bias -> H(LDS) -> fc1 MFMA ----
    #pragma unroll
    for (int c = 0; c < 4; ++c) {
        f16x8 b0f[4];
        #pragma unroll
        for (int q = 0; q < 4; ++q)
            b0f[q] = *reinterpret_cast<const f16x8*>(&pw0[((4 * c + q) * 64 + l) * 8]);
        #pragma unroll
        for (int nl = 0; nl < 2; ++nl) {
            const float bo = bias_n[2 * c + nl];
            #pragma unroll
            for (int t = 0; t < 4; ++t) {
                f32x4 acc;
                #pragma unroll
                for (int r = 0; r < 4; ++r) acc[r] = 0.f;
                acc = __builtin_amdgcn_mfma_f32_16x16x32_f16(afrag[2*t+0], b0f[2*nl+0], acc, 0, 0, 0);
                acc = __builtin_amdgcn_mfma_f32_16x16x32_f16(afrag[2*t+1], b0f[2*nl+1], acc, 0, 0, 0);
                #pragma unroll
                for (int r = 0; r < 4; ++r)   // C/D: row = 4g+r, col = lr  (m89-verified)
                    hbuf[w][16 * t + 4 * g + r][16 * nl + lr] =
                        (_Float16)fmaxf(acc[r] + bo, 0.f);
            }
        }
        __syncthreads();   // H chunk visible
        #pragma unroll
        for (int t = 0; t < 4; ++t)
            dacc[t] = __builtin_amdgcn_mfma_f32_16x16x32_f16(
                *reinterpret_cast<const f16x8*>(&hbuf[w][16 * t + lr][8 * g]),
                b1f[c], dacc[t], 0, 0, 0);
        __syncthreads();   // WAR: H read done before next chunk's write
    }

    // ---- d -> LDS (reuse ybuf), then per-pixel masked residual update ----
    float* dbuf = reinterpret_cast<float*>(&ybuf[0][0]);   // [256][20] f32
    #pragma unroll
    for (int t = 0; t < 4; ++t)
        #pragma unroll
        for (int r = 0; r < 4; ++r)
            dbuf[(64 * w + 16 * t + 4 * g + r) * 20 + lr] = dacc[t][r];
    __syncthreads();

    {
        const int j = tid & 15, i = tid >> 4;
        const int py = y0 + i, px = x0 + j;
        const size_t pix = ((size_t)bz * HWDIM + py) * HWDIM + px;
        const float m = mask[pix];
        const float4* xi = reinterpret_cast<const float4*>(&xin[pix * CH]);
        float4* xo = reinterpret_cast<float4*>(&xout[pix * CH]);
        const float* dp = &dbuf[tid * 20];
        float4 v0 = xi[0];            // channels 0..2 frozen
        v0.w += dp[3] * m;
        xo[0] = v0;
        #pragma unroll
        for (int q = 1; q < 4; ++q) {
            float4 v = xi[q];
            v.x += dp[q * 4 + 0] * m; v.y += dp[q * 4 + 1] * m;
            v.z += dp[q * 4 + 2] * m; v.w += dp[q * 4 + 3] * m;
            xo[q] = v;
        }
    }
}

// ---------------------------------------------------------------------------
__global__ __launch_bounds__(256) void nca_pool(
    const float* __restrict__ xf, float* __restrict__ pooled)
{
    __shared__ float red[256 * CH];
    const int b = blockIdx.x, tid = threadIdx.x;
    float acc[CH];
    #pragma unroll
    for (int c = 0; c < CH; ++c) acc[c] = 0.f;
    for (int p = tid; p < HWDIM * HWDIM; p += 256) {
        const float4* px = reinterpret_cast<const float4*>(
            &xf[((size_t)b * HWDIM * HWDIM + p) * CH]);
        #pragma unroll
        for (int q = 0; q < 4; ++q) {
            const float4 v = px[q];
            acc[q*4+0] += v.x; acc[q*4+1] += v.y;
            acc[q*4+2] += v.z; acc[q*4+3] += v.w;
        }
    }
    #pragma unroll
    for (int c = 0; c < CH; ++c) red[tid * CH + c] = acc[c];
    __syncthreads();
    for (int off = 128; off > 0; off >>= 1) {
        if (tid < off) {
            #pragma unroll
            for (int c = 0; c < CH; ++c)
                red[tid * CH + c] += red[(tid + off) * CH + c];
        }
        __syncthreads();
    }
    if (tid < CH)
        pooled[b * CH + tid] = red[tid] * (1.f / (HWDIM * HWDIM));
}

__global__ __launch_bounds__(128) void nca_head(
    const float* __restrict__ pooled,
    const float* __restrict__ fc2_w, const float* __restrict__ fc2_b,
    const float* __restrict__ fc3_w, const float* __restrict__ fc3_b,
    float* __restrict__ out)
{
    __shared__ float h2[HID];
    __shared__ float pl[CH];
    const int tid = threadIdx.x;
    for (int b = 0; b < NB; ++b) {
        if (tid < CH) pl[tid] = pooled[b * CH + tid];
        __syncthreads();
        float h = fc2_b[tid];
        #pragma unroll
        for (int c = 0; c < CH; ++c) h += fc2_w[tid * CH + c] * pl[c];
        h2[tid] = fmaxf(h, 0.f);
        __syncthreads();
        if (tid < 13) {
            float o = fc3_b[tid];
            #pragma unroll
            for (int jj = 0; jj < HID; ++jj) o += fc3_w[tid * HID + jj] * h2[jj];
            out[b * 13 + tid] = o;
        }
        __syncthreads();
    }
}

// ---------------------------------------------------------------------------
extern "C" void kernel_launch(void* const* d_in, const int* in_sizes, int n_in,
                              void* d_out, int out_size, void* d_ws, size_t ws_size,
                              hipStream_t stream)
{
    const float* x     = (const float*)d_in[0];
    const float* masks = (const float*)d_in[1];
    const float* fc0_w = (const float*)d_in[2];
    const float* fc0_b = (const float*)d_in[3];
    const float* fc1_w = (const float*)d_in[4];
    const float* fc2_w = (const float*)d_in[5];
    const float* fc2_b = (const float*)d_in[6];
    const float* fc3_w = (const float*)d_in[7];
    const float* fc3_b = (const float*)d_in[8];

    float*    out    = (float*)d_out;
    float*    xf     = out + NB * 13;                              // output 1 region
    float*    buf0   = (float*)d_ws;                               // ping-pong state
    float*    pooled = buf0 + (size_t)NB * HWDIM * HWDIM * CH;     // 512 f
    _Float16* pw0    = (_Float16*)(pooled + 512);                  // 16 KiB
    _Float16* pw1    = pw0 + 16 * 64 * 8;                          // 4 KiB
    float*    pb0    = (float*)(pw1 + 4 * 64 * 8);                 // 2 KiB

    nca_prepack<<<1, 256, 0, stream>>>(fc0_w, fc0_b, fc1_w, pw0, pw1, pb0);

    dim3 grid(HWDIM / 16, HWDIM / 16, NB), block(256);
    for (int s = 0; s < NSTEPS; ++s) {
        const float* in = (s == 0) ? x : ((s & 1) ? buf0 : xf);
        float* outp     = (s & 1) ? xf : buf0;
        nca_step<<<grid, block, 0, stream>>>(in, outp,
            masks + (size_t)s * NB * HWDIM * HWDIM, pw0, pb0, pw1);
    }
    nca_pool<<<NB, 256, 0, stream>>>(xf, pooled);
    nca_head<<<1, 128, 0, stream>>>(pooled, fc2_w, fc2_b, fc3_w, fc3_b, out);
}

// Round 3
// 970.140 us; speedup vs baseline: 4.6531x; 1.5724x over previous
//
#include <hip/hip_runtime.h>

#define CH     16
#define HID    128
#define HWDIM  128
#define NB     32
#define NSTEPS 32

typedef float    f32x4 __attribute__((ext_vector_type(4)));
typedef _Float16 f16x8 __attribute__((ext_vector_type(8)));

// compile-time ordering fence (0 instructions): keeps LDS writes/reads in
// program order across type-punned pool views; per-wave DS ops complete
// in order in HW, so emission order == correctness.
#define MEMBAR() asm volatile("" ::: "memory")

// ---------------------------------------------------------------------------
// Prepack weights into per-lane MFMA fragment order (fp16).
// A/B frag layout (16x16x32): lane l -> row/col = l&15, k = 8*(l>>4)+j.
// pw0: 16 frags, f = n*2+ks (n = hidden N-tile 0..7, ks = K-step, K pad 48->64)
// pw1: 4 frags,  f = ks (K over 128)
// pb0: bias replicated per lane: pb0[n*64+l] = fc0_b[16n + (l&15)]
// ---------------------------------------------------------------------------
__global__ __launch_bounds__(256) void nca_prepack(
    const float* __restrict__ w0, const float* __restrict__ b0,
    const float* __restrict__ w1,
    _Float16* __restrict__ pw0, _Float16* __restrict__ pw1, float* __restrict__ pb0)
{
    const int tid = threadIdx.x;
    for (int s = tid; s < 16 * 64; s += 256) {
        const int f = s >> 6, l = s & 63;
        const int n = f >> 1, ks = f & 1;
        const int o = 16 * n + (l & 15);
        f16x8 v;
        #pragma unroll
        for (int j = 0; j < 8; ++j) {
            const int k = 32 * ks + 8 * (l >> 4) + j;
            v[j] = (_Float16)(k < 48 ? w0[o * 48 + k] : 0.f);
        }
        *reinterpret_cast<f16x8*>(&pw0[s * 8]) = v;
    }
    for (int s = tid; s < 4 * 64; s += 256) {
        const int ks = s >> 6, l = s & 63;
        f16x8 v;
        #pragma unroll
        for (int j = 0; j < 8; ++j) {
            const int k = 32 * ks + 8 * (l >> 4) + j;
            v[j] = (_Float16)w1[(l & 15) * 128 + k];
        }
        *reinterpret_cast<f16x8*>(&pw1[s * 8]) = v;
    }
    for (int s = tid; s < 8 * 64; s += 256)
        pb0[s] = b0[16 * (s >> 6) + (s & 15)];
}

// ---------------------------------------------------------------------------
// One NCA step.  LDS pool (36864 B):
//   phase A: halo f32 pixel-major [18][18][20]          (25920 B, cross-wave)
//   phase B: per-wave 9216 B slices: ybuf[64][72]f16 -> hbuf[64][40]f16
//            -> dbuf[64][20]f32   (wave-private: NO barriers needed)
// ---------------------------------------------------------------------------
__global__ __launch_bounds__(256, 4) void nca_step(
    const float* __restrict__ xin, float* __restrict__ xout,
    const float* __restrict__ mask,
    const _Float16* __restrict__ pw0, const float* __restrict__ pb0,
    const _Float16* __restrict__ pw1)
{
    __shared__ __align__(16) char pool[36864];
    float (*halo)[18][20] = reinterpret_cast<float(*)[18][20]>(pool);

    const int bz = blockIdx.z;
    const int y0 = blockIdx.y * 16, x0 = blockIdx.x * 16;
    const int tid = threadIdx.x;

    // ---- stage halo, pixel-major f32, pitch 20 floats (bank-safe) ----
    for (int q = tid; q < 18 * 18 * 4; q += 256) {
        const int c4 = q & 3, p = q >> 2;
        const int ii = p / 18, jj = p - ii * 18;
        const int gy = y0 - 1 + ii, gx = x0 - 1 + jj;
        f32x4 v = {0.f, 0.f, 0.f, 0.f};
        if ((unsigned)gy < HWDIM && (unsigned)gx < HWDIM)
            v = *reinterpret_cast<const f32x4*>(
                &xin[(((size_t)bz * HWDIM + gy) * HWDIM + gx) * CH + 4 * c4]);
        *reinterpret_cast<f32x4*>(&halo[ii][jj][4 * c4]) = v;
    }
    __syncthreads();

    const int j = tid & 15, i = tid >> 4;
    const int li = i + 1, lj = j + 1;

    // ---- perception (f32), results as f16 in registers ----
    _Float16 idv[16], dxv[16], dyv[16];
    #pragma unroll
    for (int c4 = 0; c4 < 4; ++c4) {
        #define HLD(dy, dx) (*reinterpret_cast<const f32x4*>(&halo[li + (dy)][lj + (dx)][4 * c4]))
        const f32x4 n00 = HLD(-1,-1), n01 = HLD(-1,0), n02 = HLD(-1,1);
        const f32x4 n10 = HLD( 0,-1), n11 = HLD( 0,0), n12 = HLD( 0,1);
        const f32x4 n20 = HLD( 1,-1), n21 = HLD( 1,0), n22 = HLD( 1,1);
        #undef HLD
        const f32x4 gx = ((n02 - n00) + 2.f * (n12 - n10) + (n22 - n20)) * 0.125f;
        const f32x4 gy = ((n20 - n00) + 2.f * (n21 - n01) + (n22 - n02)) * 0.125f;
        #pragma unroll
        for (int e = 0; e < 4; ++e) {
            idv[4 * c4 + e] = (_Float16)n11[e];
            dxv[4 * c4 + e] = (_Float16)gx[e];
            dyv[4 * c4 + e] = (_Float16)gy[e];
        }
    }
    const size_t pix = ((size_t)bz * HWDIM + (y0 + i)) * HWDIM + (x0 + j);
    const float m = mask[pix];
    __syncthreads();         // last cross-wave dep: halo reads done before pool reuse

    const int w = tid >> 6, l = tid & 63;
    const int lr = l & 15,  g = l >> 4;
    char* wreg = pool + w * 9216;          // this wave's private slice

    // ---- ybuf write: own row l, pitch 144 B; cols 0..47 = y, 48..63 = 0 ----
    {
        _Float16* yrow = reinterpret_cast<_Float16*>(wreg + l * 144);
        f16x8 v;
        #pragma unroll
        for (int e = 0; e < 8; ++e) v[e] = idv[e];
        *reinterpret_cast<f16x8*>(&yrow[0]) = v;
        #pragma unroll
        for (int e = 0; e < 8; ++e) v[e] = idv[8 + e];
        *reinterpret_cast<f16x8*>(&yrow[8]) = v;
        #pragma unroll
        for (int e = 0; e < 8; ++e) v[e] = dxv[e];
        *reinterpret_cast<f16x8*>(&yrow[16]) = v;
        #pragma unroll
        for (int e = 0; e < 8; ++e) v[e] = dxv[8 + e];
        *reinterpret_cast<f16x8*>(&yrow[24]) = v;
        #pragma unroll
        for (int e = 0; e < 8; ++e) v[e] = dyv[e];
        *reinterpret_cast<f16x8*>(&yrow[32]) = v;
        #pragma unroll
        for (int e = 0; e < 8; ++e) v[e] = dyv[8 + e];
        *reinterpret_cast<f16x8*>(&yrow[40]) = v;
        f16x8 z;
        #pragma unroll
        for (int e = 0; e < 8; ++e) z[e] = (_Float16)0.f;
        *reinterpret_cast<f16x8*>(&yrow[48]) = z;
        *reinterpret_cast<f16x8*>(&yrow[56]) = z;
    }
    MEMBAR();

    // ---- A fragments from own wave's ybuf rows (in-order DS, no barrier) ----
    f16x8 afrag[8];
    #pragma unroll
    for (int t = 0; t < 4; ++t)
        #pragma unroll
        for (int ks = 0; ks < 2; ++ks)
            afrag[2 * t + ks] = *reinterpret_cast<const f16x8*>(
                wreg + (16 * t + lr) * 144 + 64 * ks + 16 * g);
    MEMBAR();

    // ---- fc1 B fragments + bias (L1-resident) ----
    f16x8 b1f[4];
    #pragma unroll
    for (int ks = 0; ks < 4; ++ks)
        b1f[ks] = *reinterpret_cast<const f16x8*>(&pw1[(ks * 64 + l) * 8]);
    float bias_n[8];
    #pragma unroll
    for (int n = 0; n < 8; ++n) bias_n[n] = pb0[n * 64 + l];

    f32x4 dacc[4];
    #pragma unroll
    for (int t = 0; t < 4; ++t)
        #pragma unroll
        for (int r = 0; r < 4; ++r) dacc[t][r] = 0.f;

    // ---- 4 chunks of 32 hidden: fc0 MFMA -> relu -> hbuf -> fc1 MFMA ----
    _Float16* hb = reinterpret_cast<_Float16*>(wreg);   // [64][40] f16, wave-private
    #pragma unroll
    for (int c = 0; c < 4; ++c) {
        f16x8 b0f[4];
        #pragma unroll
        for (int q = 0; q < 4; ++q)
            b0f[q] = *reinterpret_cast<const f16x8*>(&pw0[((4 * c + q) * 64 + l) * 8]);
        #pragma unroll
        for (int nl = 0; nl < 2; ++nl) {
            const float bo = bias_n[2 * c + nl];
            #pragma unroll
            for (int t = 0; t < 4; ++t) {
                f32x4 acc = {0.f, 0.f, 0.f, 0.f};
                acc = __builtin_amdgcn_mfma_f32_16x16x32_f16(afrag[2*t+0], b0f[2*nl+0], acc, 0, 0, 0);
                acc = __builtin_amdgcn_mfma_f32_16x16x32_f16(afrag[2*t+1], b0f[2*nl+1], acc, 0, 0, 0);
                #pragma unroll
                for (int r = 0; r < 4; ++r)    // C/D: row = 4g+r (pixel), col = lr (hidden)
                    hb[(16 * t + 4 * g + r) * 40 + 16 * nl + lr] =
                        (_Float16)fmaxf(acc[r] + bo, 0.f);
            }
        }
        MEMBAR();        // emission order; HW DS is in-order per wave
        #pragma unroll
        for (int t = 0; t < 4; ++t)
            dacc[t] = __builtin_amdgcn_mfma_f32_16x16x32_f16(
                *reinterpret_cast<const f16x8*>(&hb[(16 * t + lr) * 40 + 8 * g]),
                b1f[c], dacc[t], 0, 0, 0);
        MEMBAR();
    }

    // ---- transpose d via wave-private dbuf [64][20] f32 ----
    float* db = reinterpret_cast<float*>(wreg);
    #pragma unroll
    for (int t = 0; t < 4; ++t)
        #pragma unroll
        for (int r = 0; r < 4; ++r)
            db[(16 * t + 4 * g + r) * 20 + lr] = dacc[t][r];
    MEMBAR();

    // ---- masked residual update (first 3 channels frozen) ----
    {
        const float* dp = &db[l * 20];
        const f32x4* xi = reinterpret_cast<const f32x4*>(&xin[pix * CH]);
        f32x4* xo = reinterpret_cast<f32x4*>(&xout[pix * CH]);
        f32x4 dv = *reinterpret_cast<const f32x4*>(&dp[0]);
        f32x4 v0 = xi[0];
        v0[3] += dv[3] * m;                   // ch 0..2 frozen
        xo[0] = v0;
        #pragma unroll
        for (int q = 1; q < 4; ++q) {
            f32x4 d4 = *reinterpret_cast<const f32x4*>(&dp[4 * q]);
            f32x4 v  = xi[q];
            #pragma unroll
            for (int e = 0; e < 4; ++e) v[e] += d4[e] * m;
            xo[q] = v;
        }
    }
}

// ---------------------------------------------------------------------------
// Mean-pool, 8-way split per batch: 256 blocks, partials summed in the head.
// ---------------------------------------------------------------------------
__global__ __launch_bounds__(256) void nca_pool(
    const float* __restrict__ xf, float* __restrict__ partial)
{
    __shared__ float red[256 * CH];
    const int b = blockIdx.x >> 3, part = blockIdx.x & 7, tid = threadIdx.x;
    float acc[CH];
    #pragma unroll
    for (int c = 0; c < CH; ++c) acc[c] = 0.f;
    const int p0 = part * 2048;
    for (int p = p0 + tid; p < p0 + 2048; p += 256) {
        const f32x4* px = reinterpret_cast<const f32x4*>(
            &xf[((size_t)b * HWDIM * HWDIM + p) * CH]);
        #pragma unroll
        for (int q = 0; q < 4; ++q) {
            const f32x4 v = px[q];
            acc[q*4+0] += v[0]; acc[q*4+1] += v[1];
            acc[q*4+2] += v[2]; acc[q*4+3] += v[3];
        }
    }
    #pragma unroll
    for (int c = 0; c < CH; ++c) red[tid * CH + c] = acc[c];
    __syncthreads();
    for (int off = 128; off > 0; off >>= 1) {
        if (tid < off) {
            #pragma unroll
            for (int c = 0; c < CH; ++c)
                red[tid * CH + c] += red[(tid + off) * CH + c];
        }
        __syncthreads();
    }
    if (tid < CH)
        partial[blockIdx.x * CH + tid] = red[tid];
}

// ---------------------------------------------------------------------------
__global__ __launch_bounds__(128) void nca_head(
    const float* __restrict__ partial,
    const float* __restrict__ fc2_w, const float* __restrict__ fc2_b,
    const float* __restrict__ fc3_w, const float* __restrict__ fc3_b,
    float* __restrict__ out)
{
    __shared__ float h2[HID];
    __shared__ float pl[CH];
    const int tid = threadIdx.x;
    for (int b = 0; b < NB; ++b) {
        if (tid < CH) {
            float s = 0.f;
            #pragma unroll
            for (int q = 0; q < 8; ++q) s += partial[(b * 8 + q) * CH + tid];
            pl[tid] = s * (1.f / (HWDIM * HWDIM));
        }
        __syncthreads();
        float h = fc2_b[tid];
        #pragma unroll
        for (int c = 0; c < CH; ++c) h += fc2_w[tid * CH + c] * pl[c];
        h2[tid] = fmaxf(h, 0.f);
        __syncthreads();
        if (tid < 13) {
            float o = fc3_b[tid];
            #pragma unroll
            for (int jj = 0; jj < HID; ++jj) o += fc3_w[tid * HID + jj] * h2[jj];
            out[b * 13 + tid] = o;
        }
        __syncthreads();
    }
}

// ---------------------------------------------------------------------------
extern "C" void kernel_launch(void* const* d_in, const int* in_sizes, int n_in,
                              void* d_out, int out_size, void* d_ws, size_t ws_size,
                              hipStream_t stream)
{
    const float* x     = (const float*)d_in[0];
    const float* masks = (const float*)d_in[1];
    const float* fc0_w = (const float*)d_in[2];
    const float* fc0_b = (const float*)d_in[3];
    const float* fc1_w = (const float*)d_in[4];
    const float* fc2_w = (const float*)d_in[5];
    const float* fc2_b = (const float*)d_in[6];
    const float* fc3_w = (const float*)d_in[7];
    const float* fc3_b = (const float*)d_in[8];

    float*    out     = (float*)d_out;
    float*    xf      = out + NB * 13;                             // output 1 region
    float*    buf0    = (float*)d_ws;                              // ping-pong state
    float*    partial = buf0 + (size_t)NB * HWDIM * HWDIM * CH;    // 256*16 f
    _Float16* pw0     = (_Float16*)(partial + 256 * CH);           // 16 KiB
    _Float16* pw1     = pw0 + 16 * 64 * 8;                         // 4 KiB
    float*    pb0     = (float*)(pw1 + 4 * 64 * 8);                // 2 KiB

    nca_prepack<<<1, 256, 0, stream>>>(fc0_w, fc0_b, fc1_w, pw0, pw1, pb0);

    dim3 grid(HWDIM / 16, HWDIM / 16, NB), block(256);
    for (int s = 0; s < NSTEPS; ++s) {
        const float* in = (s == 0) ? x : ((s & 1) ? buf0 : xf);
        float* outp     = (s & 1) ? xf : buf0;
        nca_step<<<grid, block, 0, stream>>>(in, outp,
            masks + (size_t)s * NB * HWDIM * HWDIM, pw0, pb0, pw1);
    }
    nca_pool<<<NB * 8, 256, 0, stream>>>(xf, partial);
    nca_head<<<1, 128, 0, stream>>>(partial, fc2_w, fc2_b, fc3_w, fc3_b, out);
}